// Round 7
// baseline (51.723 us; speedup 1.0000x reference)
//
#include <hip/hip_runtime.h>

// 3x3 majority, replicate pad, 8 bins, ties -> smallest, 8 fused iterations.
// Bit-sliced planes (3 bits/label); one u32 = 32 columns. Wave-independent
// tiles: 64 lanes = 2 words x 32 rows (lane = w*32 + r). Input tile 64x32,
// output 48x16 (halo 8 all sides). Horizontal neighbor word via
// __shfl_xor(32); vertical rows via __shfl_up/__shfl_down(1) (natural
// self-clamp at wave ends; cross-word wrap garbage stays in halo rows).
// Image-edge replicate: column patch via bfi masks (bx edge blocks), row
// patch via cndmask at r==8 / r==23 (by edge blocks). No LDS, no barriers.
// Grid 16x48x8 = 6144 waves (~6/SIMD) for latency hiding.
//
// R6 bug fixed here: tile col t -> global col bx*48 - 8 + t, so the store
// base is bx*48 + (w ? 24 : 0)  (was +8 too far; bx=15,w=1 wrote past 767).

static constexpr int IMG = 768;
static constexpr int NBX = 16;   // 768 / 48
static constexpr int NBY = 48;   // 768 / 16

__device__ __forceinline__ unsigned bfi(unsigned m, unsigned a, unsigned b) {
  return (a & m) | (b & ~m);     // v_bfi_b32
}

struct C4 { unsigned b0, b1, b2, b3; };

__device__ __forceinline__ unsigned gt4(const C4& x, const C4& y) {  // x > y
  unsigned g = x.b0 & ~y.b0;
  unsigned a = x.b1 & ~y.b1, d = x.b1 ^ y.b1; g = (a & d) | (g & ~d);
  a = x.b2 & ~y.b2; d = x.b2 ^ y.b2; g = (a & d) | (g & ~d);
  a = x.b3 & ~y.b3; d = x.b3 ^ y.b3; g = (a & d) | (g & ~d);
  return g;
}
__device__ __forceinline__ C4 sel4(unsigned G, const C4& x, const C4& y) {
  C4 r; r.b0 = bfi(G, x.b0, y.b0); r.b1 = bfi(G, x.b1, y.b1);
  r.b2 = bfi(G, x.b2, y.b2); r.b3 = bfi(G, x.b3, y.b3); return r;
}
__device__ __forceinline__ void tourn8(const C4 c[8],
                                       unsigned& o0, unsigned& o1, unsigned& o2) {
  unsigned g01 = gt4(c[1], c[0]); C4 w01 = sel4(g01, c[1], c[0]);
  unsigned g23 = gt4(c[3], c[2]); C4 w23 = sel4(g23, c[3], c[2]);
  unsigned gA  = gt4(w23, w01);   C4 wA  = sel4(gA, w23, w01);
  unsigned iA0 = bfi(gA, g23, g01), iA1 = gA;
  unsigned g45 = gt4(c[5], c[4]); C4 w45 = sel4(g45, c[5], c[4]);
  unsigned g67 = gt4(c[7], c[6]); C4 w67 = sel4(g67, c[7], c[6]);
  unsigned gB  = gt4(w67, w45);   C4 wB  = sel4(gB, w67, w45);
  unsigned iB0 = bfi(gB, g67, g45), iB1 = gB;
  unsigned gR  = gt4(wB, wA);
  o0 = bfi(gR, iB0, iA0); o1 = bfi(gR, iB1, iA1); o2 = gR;
}

__global__ __launch_bounds__(64, 5) void fused32(
    const float* __restrict__ in, float* __restrict__ out) {
  const int bx = blockIdx.x, by = blockIdx.y, bz = blockIdx.z;
  const int lane = threadIdx.x;
  const int w = lane >> 5;       // word: cols 32w..32w+31 of the 64-wide tile
  const int r = lane & 31;       // tile row 0..31

  const float* img = in + (size_t)bz * IMG * IMG;

  // ---- stage: one clamped row-word -> 3 bit-planes
  unsigned p0 = 0, p1 = 0, p2 = 0;
  {
    int gy = by * 16 + r - 8;
    gy = gy < 0 ? 0 : (gy > IMG - 1 ? IMG - 1 : gy);
    const float* rowp = img + (size_t)gy * IMG;
    const int gx0 = bx * 48 + 32 * w - 8;
    if (gx0 >= 0 && gx0 + 32 <= IMG) {
#pragma unroll
      for (int g = 0; g < 8; ++g) {
        float4 v = *reinterpret_cast<const float4*>(rowp + gx0 + 4 * g);
        unsigned u0 = (unsigned)(int)v.x, u1 = (unsigned)(int)v.y;
        unsigned u2 = (unsigned)(int)v.z, u3 = (unsigned)(int)v.w;
        p0 |= ((u0 & 1u) | ((u1 & 1u) << 1) | ((u2 & 1u) << 2) | ((u3 & 1u) << 3)) << (4 * g);
        p1 |= (((u0 >> 1) & 1u) | (((u1 >> 1) & 1u) << 1) | (((u2 >> 1) & 1u) << 2) | (((u3 >> 1) & 1u) << 3)) << (4 * g);
        p2 |= (((u0 >> 2) & 1u) | (((u1 >> 2) & 1u) << 1) | (((u2 >> 2) & 1u) << 2) | (((u3 >> 2) & 1u) << 3)) << (4 * g);
      }
    } else {
#pragma unroll
      for (int j = 0; j < 32; ++j) {
        int gx = gx0 + j; gx = gx < 0 ? 0 : (gx > IMG - 1 ? IMG - 1 : gx);
        unsigned u = (unsigned)(int)rowp[gx];
        p0 |= (u & 1u) << j;
        p1 |= ((u >> 1) & 1u) << j;
        p2 |= ((u >> 2) & 1u) << j;
      }
    }
  }

  const bool edgeX = (bx == 0) || (bx == NBX - 1);
  const unsigned maskL = (bx == 0 && w == 0) ? 0x100u : 0u;          // tile col 8
  const unsigned maskR = (bx == NBX - 1 && w == 1) ? 0x00800000u : 0u; // tile col 55
  const bool topE = (by == 0), botE = (by == NBY - 1);
  const bool isR8 = (r == 8), isR23 = (r == 23);

#pragma unroll 1
  for (int it = 0; it < 8; ++it) {
    // equality masks from planes
    unsigned e[8];
    {
      unsigned n0 = ~p0, n1 = ~p1, n2 = ~p2;
      unsigned a00 = n1 & n0, a01 = n1 & p0, a10 = p1 & n0, a11 = p1 & p0;
      e[0] = n2 & a00; e[1] = n2 & a01; e[2] = n2 & a10; e[3] = n2 & a11;
      e[4] = p2 & a00; e[5] = p2 & a01; e[6] = p2 & a10; e[7] = p2 & a11;
    }

    // horizontal 2-bit counts per bin (needs other word's mask, same row)
    unsigned HL[8], HH[8];
#pragma unroll
    for (int b = 0; b < 8; ++b) {
      unsigned n = (unsigned)__shfl_xor((int)e[b], 32, 64);
      unsigned A = __builtin_amdgcn_alignbit(e[b], n, 31);  // (e<<1)|(n>>31)
      unsigned C = __builtin_amdgcn_alignbit(n, e[b], 1);   // (e>>1)|(n<<31)
      if (edgeX) { A = bfi(maskL, e[b], A); C = bfi(maskR, e[b], C); }
      unsigned t = A ^ e[b];
      HL[b] = t ^ C;
      HH[b] = bfi(t, C, e[b]);   // majority(A, e, C)
    }

    // vertical 3-row sum (2b+2b+2b -> 4b) per bin, neighbors via shfl
    C4 c[8];
#pragma unroll
    for (int b = 0; b < 8; ++b) {
      unsigned HmL = (unsigned)__shfl_up((int)HL[b], 1, 64);
      unsigned HmH = (unsigned)__shfl_up((int)HH[b], 1, 64);
      unsigned HqL = (unsigned)__shfl_down((int)HL[b], 1, 64);
      unsigned HqH = (unsigned)__shfl_down((int)HH[b], 1, 64);
      if (topE) { HmL = isR8 ? HL[b] : HmL; HmH = isR8 ? HH[b] : HmH; }
      if (botE) { HqL = isR23 ? HL[b] : HqL; HqH = isR23 ? HH[b] : HqH; }
      unsigned s0 = HmL ^ HL[b], cc = HmL & HL[b];
      unsigned u  = HmH ^ HH[b];
      unsigned s1 = u ^ cc, s2 = bfi(u, cc, HH[b]);
      unsigned t0 = s0 ^ HqL, k0 = s0 & HqL, v = s1 ^ HqH;
      c[b].b0 = t0; c[b].b1 = v ^ k0;
      unsigned k1 = bfi(v, k0, HqH);
      c[b].b2 = s2 ^ k1; c[b].b3 = s2 & k1;
    }

    tourn8(c, p0, p1, p2);
  }

  // ---- store: valid rows 8..23 (tile), valid cols: w=0 bits 8..31 -> global
  // bx*48 + 0..23; w=1 bits 0..23 -> global bx*48 + 24..47.
  if (r >= 8 && r < 24) {
    const int gy = by * 16 + r - 8;
    float* orow = out + (size_t)bz * IMG * IMG + (size_t)gy * IMG
                + bx * 48 + (w ? 24 : 0);
    const int jb = w ? 0 : 8;
#pragma unroll
    for (int g = 0; g < 6; ++g) {
      const int j = jb + 4 * g;
      float4 v;
      v.x = (float)(((p0 >> (j + 0)) & 1u) | (((p1 >> (j + 0)) & 1u) << 1) | (((p2 >> (j + 0)) & 1u) << 2));
      v.y = (float)(((p0 >> (j + 1)) & 1u) | (((p1 >> (j + 1)) & 1u) << 1) | (((p2 >> (j + 1)) & 1u) << 2));
      v.z = (float)(((p0 >> (j + 2)) & 1u) | (((p1 >> (j + 2)) & 1u) << 1) | (((p2 >> (j + 2)) & 1u) << 2));
      v.w = (float)(((p0 >> (j + 3)) & 1u) | (((p1 >> (j + 3)) & 1u) << 1) | (((p2 >> (j + 3)) & 1u) << 2));
      *reinterpret_cast<float4*>(orow + 4 * g) = v;
    }
  }
}

extern "C" void kernel_launch(void* const* d_in, const int* in_sizes, int n_in,
                              void* d_out, int out_size, void* d_ws, size_t ws_size,
                              hipStream_t stream) {
  const float* clusters = (const float*)d_in[0];
  (void)in_sizes; (void)n_in; (void)out_size; (void)d_ws; (void)ws_size;

  dim3 grid(NBX, NBY, 8);   // 16 x 48 tiles x batch 8, one wave per tile
  fused32<<<grid, 64, 0, stream>>>(clusters, (float*)d_out);
}

// Round 8
// 51.329 us; speedup vs baseline: 1.0077x; 1.0077x over previous
//
#include <hip/hip_runtime.h>

// 3x3 majority, replicate pad, 8 bins, ties -> smallest, 8 fused iterations.
// Bit-sliced planes (3 bits/label); one u32 = 32 columns (bits = cols).
// Wave-independent tiles: 64 lanes = 2 words x 32 rows (lane = w*32 + r).
// Input tile 64x32, output 48x16 (halo 8 all sides). 4 independent waves per
// 256-thread block (beats the workgroup-per-CU cap; 6 blocks/CU exactly).
// Cross-lane via raw ds_bpermute with HOISTED addresses (vUp,vDn,vXw).
// Order: vertical 3-count of eq-masks first (lane +-1), then horizontal
// 3-sum via alignbit + cross-word word (lane^32). Tournament argmax with
// (x^y)&x + bfi merge (11 insts/compare). Wrap garbage stays in the halo.
// Image-edge replicate: row patch (r==8 / r==23 on by-edge), col patch via
// bfi masks (bit 8 of w0 / bit 23 of w1 on bx-edge).

static constexpr int IMG = 768;
static constexpr int NBX = 16;   // 768 / 48
static constexpr int NBY = 48;   // 768 / 16

__device__ __forceinline__ unsigned bfi(unsigned m, unsigned a, unsigned b) {
  return (a & m) | (b & ~m);     // v_bfi_b32
}
__device__ __forceinline__ unsigned bperm(int addr, unsigned v) {
  return (unsigned)__builtin_amdgcn_ds_bpermute(addr, (int)v);
}

struct C4 { unsigned b0, b1, b2, b3; };

__device__ __forceinline__ unsigned gt4(const C4& x, const C4& y) {  // x > y
  unsigned d = x.b0 ^ y.b0;
  unsigned g = d & x.b0;                       // x0 & ~y0
  d = x.b1 ^ y.b1; g = bfi(d, d & x.b1, g);
  d = x.b2 ^ y.b2; g = bfi(d, d & x.b2, g);
  d = x.b3 ^ y.b3; g = bfi(d, d & x.b3, g);
  return g;
}
__device__ __forceinline__ C4 sel4(unsigned G, const C4& x, const C4& y) {
  C4 r; r.b0 = bfi(G, x.b0, y.b0); r.b1 = bfi(G, x.b1, y.b1);
  r.b2 = bfi(G, x.b2, y.b2); r.b3 = bfi(G, x.b3, y.b3); return r;
}
__device__ __forceinline__ void tourn8(const C4 c[8],
                                       unsigned& o0, unsigned& o1, unsigned& o2) {
  unsigned g01 = gt4(c[1], c[0]); C4 w01 = sel4(g01, c[1], c[0]);
  unsigned g23 = gt4(c[3], c[2]); C4 w23 = sel4(g23, c[3], c[2]);
  unsigned gA  = gt4(w23, w01);   C4 wA  = sel4(gA, w23, w01);
  unsigned iA0 = bfi(gA, g23, g01), iA1 = gA;
  unsigned g45 = gt4(c[5], c[4]); C4 w45 = sel4(g45, c[5], c[4]);
  unsigned g67 = gt4(c[7], c[6]); C4 w67 = sel4(g67, c[7], c[6]);
  unsigned gB  = gt4(w67, w45);   C4 wB  = sel4(gB, w67, w45);
  unsigned iB0 = bfi(gB, g67, g45), iB1 = gB;
  unsigned gR  = gt4(wB, wA);
  o0 = bfi(gR, iB0, iA0); o1 = bfi(gR, iB1, iA1); o2 = gR;
}

__global__ __launch_bounds__(256, 6) void fused32(
    const float* __restrict__ in, float* __restrict__ out) {
  const int wave = threadIdx.x >> 6;
  const int lane = threadIdx.x & 63;
  const int bx = blockIdx.x * 4 + wave;   // 0..15
  const int by = blockIdx.y, bz = blockIdx.z;
  const int w = lane >> 5;       // word: cols 32w..32w+31 of the 64-wide tile
  const int r = lane & 31;       // tile row 0..31

  const float* img = in + (size_t)bz * IMG * IMG;

  // hoisted bpermute addresses (lane index * 4)
  const int vUp = ((lane - 1) & 63) << 2;
  const int vDn = ((lane + 1) & 63) << 2;
  const int vXw = (lane ^ 32) << 2;

  // ---- stage: one clamped row-word -> 3 bit-planes
  unsigned p0 = 0, p1 = 0, p2 = 0;
  {
    int gy = by * 16 + r - 8;
    gy = gy < 0 ? 0 : (gy > IMG - 1 ? IMG - 1 : gy);
    const float* rowp = img + (size_t)gy * IMG;
    const int gx0 = bx * 48 + 32 * w - 8;
    if (gx0 >= 0 && gx0 + 32 <= IMG) {
#pragma unroll
      for (int g = 0; g < 8; ++g) {
        float4 v = *reinterpret_cast<const float4*>(rowp + gx0 + 4 * g);
        unsigned u0 = (unsigned)(int)v.x, u1 = (unsigned)(int)v.y;
        unsigned u2 = (unsigned)(int)v.z, u3 = (unsigned)(int)v.w;
        p0 |= ((u0 & 1u) | ((u1 & 1u) << 1) | ((u2 & 1u) << 2) | ((u3 & 1u) << 3)) << (4 * g);
        p1 |= (((u0 >> 1) & 1u) | (((u1 >> 1) & 1u) << 1) | (((u2 >> 1) & 1u) << 2) | (((u3 >> 1) & 1u) << 3)) << (4 * g);
        p2 |= (((u0 >> 2) & 1u) | (((u1 >> 2) & 1u) << 1) | (((u2 >> 2) & 1u) << 2) | (((u3 >> 2) & 1u) << 3)) << (4 * g);
      }
    } else {
#pragma unroll
      for (int j = 0; j < 32; ++j) {
        int gx = gx0 + j; gx = gx < 0 ? 0 : (gx > IMG - 1 ? IMG - 1 : gx);
        unsigned u = (unsigned)(int)rowp[gx];
        p0 |= (u & 1u) << j;
        p1 |= ((u >> 1) & 1u) << j;
        p2 |= ((u >> 2) & 1u) << j;
      }
    }
  }

  const bool edgeX = (bx == 0) || (bx == NBX - 1);
  const unsigned maskL = (bx == 0 && w == 0) ? 0x100u : 0u;            // tile col 8
  const unsigned maskR = (bx == NBX - 1 && w == 1) ? 0x00800000u : 0u; // tile col 55
  const bool topE = (by == 0), botE = (by == NBY - 1);
  const bool isR8 = (r == 8), isR23 = (r == 23);

#pragma unroll 1
  for (int it = 0; it < 8; ++it) {
    // equality masks from planes (15 ops)
    unsigned e[8];
    {
      unsigned n0 = ~p0, n1 = ~p1, n2 = ~p2;
      unsigned a00 = n1 & n0, a01 = n1 & p0, a10 = p1 & n0, a11 = p1 & p0;
      e[0] = n2 & a00; e[1] = n2 & a01; e[2] = n2 & a10; e[3] = n2 & a11;
      e[4] = p2 & a00; e[5] = p2 & a01; e[6] = p2 & a10; e[7] = p2 & a11;
    }

    // vertical 2-bit 3-count per bin: rows r-1, r, r+1 via bpermute
    unsigned VL[8], VH[8];
#pragma unroll
    for (int b = 0; b < 8; ++b) {
      unsigned eu = bperm(vUp, e[b]);
      unsigned ed = bperm(vDn, e[b]);
      if (topE) eu = isR8 ? e[b] : eu;    // image row 0: up -> self
      if (botE) ed = isR23 ? e[b] : ed;   // image row 767: down -> self
      unsigned t = eu ^ e[b];
      VL[b] = t ^ ed;
      VH[b] = bfi(t, ed, e[b]);           // majority(eu, e, ed)
    }

    // horizontal 3-sum of V (2b+2b+2b -> 4b) per bin; cross-word via lane^32
    C4 c[8];
#pragma unroll
    for (int b = 0; b < 8; ++b) {
      unsigned nL = bperm(vXw, VL[b]);
      unsigned nH = bperm(vXw, VH[b]);
      unsigned A0 = __builtin_amdgcn_alignbit(VL[b], nL, 31);  // (V<<1)|(n>>31)
      unsigned A1 = __builtin_amdgcn_alignbit(VH[b], nH, 31);
      unsigned C0 = __builtin_amdgcn_alignbit(nL, VL[b], 1);   // (V>>1)|(n<<31)
      unsigned C1 = __builtin_amdgcn_alignbit(nH, VH[b], 1);
      if (edgeX) {
        A0 = bfi(maskL, VL[b], A0); A1 = bfi(maskL, VH[b], A1);
        C0 = bfi(maskR, VL[b], C0); C1 = bfi(maskR, VH[b], C1);
      }
      unsigned s0 = A0 ^ VL[b], cc = A0 & VL[b];
      unsigned u  = A1 ^ VH[b];
      unsigned s1 = u ^ cc, s2 = bfi(u, cc, VH[b]);
      unsigned t0 = s0 ^ C0, k0 = s0 & C0, v = s1 ^ C1;
      c[b].b0 = t0; c[b].b1 = v ^ k0;
      unsigned k1 = bfi(v, k0, C1);
      c[b].b2 = s2 ^ k1; c[b].b3 = s2 & k1;
    }

    tourn8(c, p0, p1, p2);
  }

  // ---- store: valid rows 8..23 (tile); w=0 bits 8..31 -> global bx*48+0..23,
  // w=1 bits 0..23 -> global bx*48+24..47.
  if (r >= 8 && r < 24) {
    const int gy = by * 16 + r - 8;
    float* orow = out + (size_t)bz * IMG * IMG + (size_t)gy * IMG
                + bx * 48 + (w ? 24 : 0);
    const int jb = w ? 0 : 8;
#pragma unroll
    for (int g = 0; g < 6; ++g) {
      const int j = jb + 4 * g;
      float4 v;
      v.x = (float)(((p0 >> (j + 0)) & 1u) | (((p1 >> (j + 0)) & 1u) << 1) | (((p2 >> (j + 0)) & 1u) << 2));
      v.y = (float)(((p0 >> (j + 1)) & 1u) | (((p1 >> (j + 1)) & 1u) << 1) | (((p2 >> (j + 1)) & 1u) << 2));
      v.z = (float)(((p0 >> (j + 2)) & 1u) | (((p1 >> (j + 2)) & 1u) << 1) | (((p2 >> (j + 2)) & 1u) << 2));
      v.w = (float)(((p0 >> (j + 3)) & 1u) | (((p1 >> (j + 3)) & 1u) << 1) | (((p2 >> (j + 3)) & 1u) << 2));
      *reinterpret_cast<float4*>(orow + 4 * g) = v;
    }
  }
}

extern "C" void kernel_launch(void* const* d_in, const int* in_sizes, int n_in,
                              void* d_out, int out_size, void* d_ws, size_t ws_size,
                              hipStream_t stream) {
  const float* clusters = (const float*)d_in[0];
  (void)in_sizes; (void)n_in; (void)out_size; (void)d_ws; (void)ws_size;

  // 4 tiles (waves) per block: grid.x * 4 = 16 x-tiles; 1536 blocks total.
  dim3 grid(4, NBY, 8);
  fused32<<<grid, 256, 0, stream>>>(clusters, (float*)d_out);
}

// Round 9
// 45.360 us; speedup vs baseline: 1.1403x; 1.1316x over previous
//
#include <hip/hip_runtime.h>

// 3x3 majority, replicate pad, 8 bins, ties -> smallest, 8 fused iterations.
// Bit-sliced planes (3 bits/label); one u32 = 32 columns (bits = cols).
// Block = 4 waves = 64x128-px input tile (2 words x 128 rows; lane = w*32+r,
// wave v owns rows 32v..32v+31), output 48x112 (halo 8 in x, 8 in y).
// Vertical neighbors: in-wave via ds_bpermute (lane +-1); across wave
// boundaries via a 1 KB LDS exchange of the two boundary e-mask rows per
// wave, double-buffered, ONE barrier per iteration. Horizontal: cross-word
// via bpermute lane^32 + alignbit funnels. Tournament argmax (strict >,
// scan order => first max = smallest bin). Tile-edge wrap garbage stays in
// the 8-px halo (1 px/iter). Image-edge replicate: per-lane row predicates
// (gy==0 / gy==767) + column bfi masks on bx-edge blocks.
// Grid 16 x 7 x 8 = 896 blocks (all co-resident), work = 28,672 wave-iters
// (0.58x of R8's 49,152).

static constexpr int IMG = 768;
static constexpr int NBX = 16;   // x tiles (48 cols each, exact)
static constexpr int NBY = 7;    // y tiles (112 rows each, last overhangs 16)

__device__ __forceinline__ unsigned bfi(unsigned m, unsigned a, unsigned b) {
  return (a & m) | (b & ~m);     // v_bfi_b32
}
__device__ __forceinline__ unsigned bperm(int addr, unsigned v) {
  return (unsigned)__builtin_amdgcn_ds_bpermute(addr, (int)v);
}

struct C4 { unsigned b0, b1, b2, b3; };

__device__ __forceinline__ unsigned gt4(const C4& x, const C4& y) {  // x > y
  unsigned d = x.b0 ^ y.b0;
  unsigned g = d & x.b0;
  d = x.b1 ^ y.b1; g = bfi(d, d & x.b1, g);
  d = x.b2 ^ y.b2; g = bfi(d, d & x.b2, g);
  d = x.b3 ^ y.b3; g = bfi(d, d & x.b3, g);
  return g;
}
__device__ __forceinline__ C4 sel4(unsigned G, const C4& x, const C4& y) {
  C4 r; r.b0 = bfi(G, x.b0, y.b0); r.b1 = bfi(G, x.b1, y.b1);
  r.b2 = bfi(G, x.b2, y.b2); r.b3 = bfi(G, x.b3, y.b3); return r;
}
__device__ __forceinline__ void tourn8(const C4 c[8],
                                       unsigned& o0, unsigned& o1, unsigned& o2) {
  unsigned g01 = gt4(c[1], c[0]); C4 w01 = sel4(g01, c[1], c[0]);
  unsigned g23 = gt4(c[3], c[2]); C4 w23 = sel4(g23, c[3], c[2]);
  unsigned gA  = gt4(w23, w01);   C4 wA  = sel4(gA, w23, w01);
  unsigned iA0 = bfi(gA, g23, g01), iA1 = gA;
  unsigned g45 = gt4(c[5], c[4]); C4 w45 = sel4(g45, c[5], c[4]);
  unsigned g67 = gt4(c[7], c[6]); C4 w67 = sel4(g67, c[7], c[6]);
  unsigned gB  = gt4(w67, w45);   C4 wB  = sel4(gB, w67, w45);
  unsigned iB0 = bfi(gB, g67, g45), iB1 = gB;
  unsigned gR  = gt4(wB, wA);
  o0 = bfi(gR, iB0, iA0); o1 = bfi(gR, iB1, iA1); o2 = gR;
}

__global__ __launch_bounds__(256, 4) void fused128(
    const float* __restrict__ in, float* __restrict__ out) {
  const int tid = threadIdx.x;
  const int v = tid >> 6;          // wave 0..3
  const int lane = tid & 63;
  const int w = lane >> 5;         // word: cols 32w..32w+31 of 64-wide tile
  const int r = lane & 31;         // in-wave row
  const int trow = (v << 5) | r;   // tile row 0..127
  const int bx = blockIdx.x, by = blockIdx.y, bz = blockIdx.z;

  // [dbuf][top=0/bot=1][wave][word][bin]
  __shared__ unsigned xch[2][2][4][2][8];

  const float* img = in + (size_t)bz * IMG * IMG;
  const int gyu = by * 112 + trow - 8;   // unclamped global row

  // ---- stage: one clamped row-word -> 3 bit-planes
  unsigned p0 = 0, p1 = 0, p2 = 0;
  {
    int gy = gyu < 0 ? 0 : (gyu > IMG - 1 ? IMG - 1 : gyu);
    const float* rowp = img + (size_t)gy * IMG;
    const int gx0 = bx * 48 + 32 * w - 8;
    if (gx0 >= 0 && gx0 + 32 <= IMG) {
#pragma unroll
      for (int g = 0; g < 8; ++g) {
        float4 f = *reinterpret_cast<const float4*>(rowp + gx0 + 4 * g);
        unsigned u0 = (unsigned)(int)f.x, u1 = (unsigned)(int)f.y;
        unsigned u2 = (unsigned)(int)f.z, u3 = (unsigned)(int)f.w;
        p0 |= ((u0 & 1u) | ((u1 & 1u) << 1) | ((u2 & 1u) << 2) | ((u3 & 1u) << 3)) << (4 * g);
        p1 |= (((u0 >> 1) & 1u) | (((u1 >> 1) & 1u) << 1) | (((u2 >> 1) & 1u) << 2) | (((u3 >> 1) & 1u) << 3)) << (4 * g);
        p2 |= (((u0 >> 2) & 1u) | (((u1 >> 2) & 1u) << 1) | (((u2 >> 2) & 1u) << 2) | (((u3 >> 2) & 1u) << 3)) << (4 * g);
      }
    } else {
#pragma unroll
      for (int j = 0; j < 32; ++j) {
        int gx = gx0 + j; gx = gx < 0 ? 0 : (gx > IMG - 1 ? IMG - 1 : gx);
        unsigned u = (unsigned)(int)rowp[gx];
        p0 |= (u & 1u) << j;
        p1 |= ((u >> 1) & 1u) << j;
        p2 |= ((u >> 2) & 1u) << j;
      }
    }
  }

  // hoisted bpermute addresses
  const int vUp = ((lane - 1) & 63) << 2;
  const int vDn = ((lane + 1) & 63) << 2;
  const int vXw = (lane ^ 32) << 2;

  const bool isTop = (r == 0), isBot = (r == 31);
  const bool topE = (by == 0), botE = (by == NBY - 1);
  const bool topI = (gyu == 0), botI = (gyu == IMG - 1);
  const bool edgeX = (bx == 0) || (bx == NBX - 1);
  const unsigned maskL = (bx == 0 && w == 0) ? 0x100u : 0u;            // tile col 8
  const unsigned maskR = (bx == NBX - 1 && w == 1) ? 0x00800000u : 0u; // tile col 55
  const int vu = v > 0 ? v - 1 : 0;
  const int vd = v < 3 ? v + 1 : 3;

#pragma unroll 1
  for (int it = 0; it < 8; ++it) {
    // equality masks from planes (15 ops)
    unsigned e[8];
    {
      unsigned n0 = ~p0, n1 = ~p1, n2 = ~p2;
      unsigned a00 = n1 & n0, a01 = n1 & p0, a10 = p1 & n0, a11 = p1 & p0;
      e[0] = n2 & a00; e[1] = n2 & a01; e[2] = n2 & a10; e[3] = n2 & a11;
      e[4] = p2 & a00; e[5] = p2 & a01; e[6] = p2 & a10; e[7] = p2 & a11;
    }

    // ---- cross-wave boundary exchange of e-masks (dbuf on it&1)
    const int db = it & 1;
    if (isTop) {
      *(uint4*)&xch[db][0][v][w][0] = make_uint4(e[0], e[1], e[2], e[3]);
      *(uint4*)&xch[db][0][v][w][4] = make_uint4(e[4], e[5], e[6], e[7]);
    }
    if (isBot) {
      *(uint4*)&xch[db][1][v][w][0] = make_uint4(e[0], e[1], e[2], e[3]);
      *(uint4*)&xch[db][1][v][w][4] = make_uint4(e[4], e[5], e[6], e[7]);
    }
    __syncthreads();
    uint4 u0 = *(const uint4*)&xch[db][1][vu][w][0];  // up = wave v-1 bottom
    uint4 u1 = *(const uint4*)&xch[db][1][vu][w][4];
    uint4 d0 = *(const uint4*)&xch[db][0][vd][w][0];  // down = wave v+1 top
    uint4 d1 = *(const uint4*)&xch[db][0][vd][w][4];
    const unsigned eU[8] = {u0.x, u0.y, u0.z, u0.w, u1.x, u1.y, u1.z, u1.w};
    const unsigned eD[8] = {d0.x, d0.y, d0.z, d0.w, d1.x, d1.y, d1.z, d1.w};

    // vertical 2-bit 3-count per bin (rows r-1, r, r+1)
    unsigned VL[8], VH[8];
#pragma unroll
    for (int b = 0; b < 8; ++b) {
      unsigned eu = bperm(vUp, e[b]);
      unsigned ed = bperm(vDn, e[b]);
      eu = isTop ? eU[b] : eu;            // cross-wave up
      ed = isBot ? eD[b] : ed;            // cross-wave down
      if (topE) eu = topI ? e[b] : eu;    // image row 0 replicate
      if (botE) ed = botI ? e[b] : ed;    // image row 767 replicate
      unsigned t = eu ^ e[b];
      VL[b] = t ^ ed;
      VH[b] = bfi(t, ed, e[b]);           // majority(eu, e, ed)
    }

    // horizontal 3-sum of V (2b+2b+2b -> 4b); cross-word via lane^32
    C4 c[8];
#pragma unroll
    for (int b = 0; b < 8; ++b) {
      unsigned nL = bperm(vXw, VL[b]);
      unsigned nH = bperm(vXw, VH[b]);
      unsigned A0 = __builtin_amdgcn_alignbit(VL[b], nL, 31);
      unsigned A1 = __builtin_amdgcn_alignbit(VH[b], nH, 31);
      unsigned C0 = __builtin_amdgcn_alignbit(nL, VL[b], 1);
      unsigned C1 = __builtin_amdgcn_alignbit(nH, VH[b], 1);
      if (edgeX) {
        A0 = bfi(maskL, VL[b], A0); A1 = bfi(maskL, VH[b], A1);
        C0 = bfi(maskR, VL[b], C0); C1 = bfi(maskR, VH[b], C1);
      }
      unsigned s0 = A0 ^ VL[b], cc = A0 & VL[b];
      unsigned u  = A1 ^ VH[b];
      unsigned s1 = u ^ cc, s2 = bfi(u, cc, VH[b]);
      unsigned t0 = s0 ^ C0, k0 = s0 & C0, vv = s1 ^ C1;
      c[b].b0 = t0; c[b].b1 = vv ^ k0;
      unsigned k1 = bfi(vv, k0, C1);
      c[b].b2 = s2 ^ k1; c[b].b3 = s2 & k1;
    }

    tourn8(c, p0, p1, p2);
  }

  // ---- store: valid tile rows 8..119, gy < 768; w=0 bits 8..31 -> global
  // bx*48+0..23, w=1 bits 0..23 -> bx*48+24..47.
  if (trow >= 8 && trow < 120 && gyu < IMG) {
    float* orow = out + (size_t)bz * IMG * IMG + (size_t)gyu * IMG
                + bx * 48 + (w ? 24 : 0);
    const int jb = w ? 0 : 8;
#pragma unroll
    for (int g = 0; g < 6; ++g) {
      const int j = jb + 4 * g;
      float4 f;
      f.x = (float)(((p0 >> (j + 0)) & 1u) | (((p1 >> (j + 0)) & 1u) << 1) | (((p2 >> (j + 0)) & 1u) << 2));
      f.y = (float)(((p0 >> (j + 1)) & 1u) | (((p1 >> (j + 1)) & 1u) << 1) | (((p2 >> (j + 1)) & 1u) << 2));
      f.z = (float)(((p0 >> (j + 2)) & 1u) | (((p1 >> (j + 2)) & 1u) << 1) | (((p2 >> (j + 2)) & 1u) << 2));
      f.w = (float)(((p0 >> (j + 3)) & 1u) | (((p1 >> (j + 3)) & 1u) << 1) | (((p2 >> (j + 3)) & 1u) << 2));
      *reinterpret_cast<float4*>(orow + 4 * g) = f;
    }
  }
}

extern "C" void kernel_launch(void* const* d_in, const int* in_sizes, int n_in,
                              void* d_out, int out_size, void* d_ws, size_t ws_size,
                              hipStream_t stream) {
  const float* clusters = (const float*)d_in[0];
  (void)in_sizes; (void)n_in; (void)out_size; (void)d_ws; (void)ws_size;

  dim3 grid(NBX, NBY, 8);   // 16 x 7 tiles x batch 8; 4 waves per block
  fused128<<<grid, 256, 0, stream>>>(clusters, (float*)d_out);
}

// Round 10
// 40.286 us; speedup vs baseline: 1.2839x; 1.1259x over previous
//
#include <hip/hip_runtime.h>

// 3x3 majority, replicate pad, 8 bins, ties -> smallest, 8 fused iterations.
// Bit-sliced planes (3 bits/label). Lane = one FULL tile row of 64 px as a
// u64 (two u32 words: word0 = tile cols 0..31, word1 = 32..63). Wave = 64
// rows x 64 cols input tile -> 48x48 output (halo 8). 4 independent waves
// per 256-thread block; grid 4x16x8 = 2048 waves.
//   horizontal: in-lane u64 funnel shifts (v_lshl/lshr + v_alignbit) - no
//     cross-lane ops at all.
//   vertical:   rows +-1 via DPP wave_shr1 (0x138, lane i <- i-1) and
//     wave_shl1 (0x130, lane i <- i+1) - VALU-pipe, no DS ops, no barrier.
//     Wave-end garbage (lanes 0/63) stays in the 8-row halo (1 row/iter).
// Argmax: running strict-> scan over bins 0..7 (first max = smallest label).
// Image-edge replicate: row patch via cndmask at lane 8/55 on by-edge
// blocks; col patch via bfi of bit 8 (word0) / bit 23 (word1) on bx-edge.

static constexpr int IMG = 768;
static constexpr int NBX = 16;   // 768/48 x-tiles
static constexpr int NBY = 16;   // 768/48 y-tiles

__device__ __forceinline__ unsigned bfi(unsigned m, unsigned a, unsigned b) {
  return (a & m) | (b & ~m);     // v_bfi_b32
}
__device__ __forceinline__ unsigned dppUp(unsigned x) {   // lane i <- lane i-1
  return (unsigned)__builtin_amdgcn_update_dpp(0, (int)x, 0x138, 0xF, 0xF, false);
}
__device__ __forceinline__ unsigned dppDn(unsigned x) {   // lane i <- lane i+1
  return (unsigned)__builtin_amdgcn_update_dpp(0, (int)x, 0x130, 0xF, 0xF, false);
}
__device__ __forceinline__ unsigned alignb(unsigned hi, unsigned lo, int s) {
  return __builtin_amdgcn_alignbit(hi, lo, s);   // ((hi:lo) >> s) low 32
}

__global__ __launch_bounds__(256) void fused_dpp(
    const float* __restrict__ in, float* __restrict__ out) {
  const int wv = threadIdx.x >> 6;
  const int lane = threadIdx.x & 63;
  const int bx = blockIdx.x * 4 + wv;          // 0..15
  const int by = blockIdx.y, bz = blockIdx.z;

  const float* img = in + (size_t)bz * IMG * IMG;
  const int gyu = by * 48 - 8 + lane;          // unclamped global row

  // ---- stage: one clamped 64-px row -> 6 plane words
  unsigned p0l = 0, p1l = 0, p2l = 0, p0h = 0, p1h = 0, p2h = 0;
  {
    int gy = gyu < 0 ? 0 : (gyu > IMG - 1 ? IMG - 1 : gyu);
    const float* rp = img + (size_t)gy * IMG;
    const int gx0 = bx * 48 - 8;
    if (gx0 >= 0 && gx0 + 64 <= IMG) {
#pragma unroll
      for (int g = 0; g < 8; ++g) {
        float4 f = *reinterpret_cast<const float4*>(rp + gx0 + 4 * g);
        unsigned u0 = (unsigned)(int)f.x, u1 = (unsigned)(int)f.y;
        unsigned u2 = (unsigned)(int)f.z, u3 = (unsigned)(int)f.w;
        p0l |= ((u0 & 1u) | ((u1 & 1u) << 1) | ((u2 & 1u) << 2) | ((u3 & 1u) << 3)) << (4 * g);
        p1l |= (((u0 >> 1) & 1u) | (((u1 >> 1) & 1u) << 1) | (((u2 >> 1) & 1u) << 2) | (((u3 >> 1) & 1u) << 3)) << (4 * g);
        p2l |= (((u0 >> 2) & 1u) | (((u1 >> 2) & 1u) << 1) | (((u2 >> 2) & 1u) << 2) | (((u3 >> 2) & 1u) << 3)) << (4 * g);
      }
#pragma unroll
      for (int g = 0; g < 8; ++g) {
        float4 f = *reinterpret_cast<const float4*>(rp + gx0 + 32 + 4 * g);
        unsigned u0 = (unsigned)(int)f.x, u1 = (unsigned)(int)f.y;
        unsigned u2 = (unsigned)(int)f.z, u3 = (unsigned)(int)f.w;
        p0h |= ((u0 & 1u) | ((u1 & 1u) << 1) | ((u2 & 1u) << 2) | ((u3 & 1u) << 3)) << (4 * g);
        p1h |= (((u0 >> 1) & 1u) | (((u1 >> 1) & 1u) << 1) | (((u2 >> 1) & 1u) << 2) | (((u3 >> 1) & 1u) << 3)) << (4 * g);
        p2h |= (((u0 >> 2) & 1u) | (((u1 >> 2) & 1u) << 1) | (((u2 >> 2) & 1u) << 2) | (((u3 >> 2) & 1u) << 3)) << (4 * g);
      }
    } else {
#pragma unroll
      for (int j = 0; j < 32; ++j) {
        int gx = gx0 + j; gx = gx < 0 ? 0 : (gx > IMG - 1 ? IMG - 1 : gx);
        unsigned u = (unsigned)(int)rp[gx];
        p0l |= (u & 1u) << j; p1l |= ((u >> 1) & 1u) << j; p2l |= ((u >> 2) & 1u) << j;
        gx = gx0 + 32 + j; gx = gx < 0 ? 0 : (gx > IMG - 1 ? IMG - 1 : gx);
        u = (unsigned)(int)rp[gx];
        p0h |= (u & 1u) << j; p1h |= ((u >> 1) & 1u) << j; p2h |= ((u >> 2) & 1u) << j;
      }
    }
  }

  const bool topE = (by == 0), botE = (by == NBY - 1);
  const bool lxE = (bx == 0), rxE = (bx == NBX - 1);
  const bool pTop = (lane == 8);    // image row 0 (gyu==0) when by==0
  const bool pBot = (lane == 55);   // image row 767 when by==15

#pragma unroll 1
  for (int it = 0; it < 8; ++it) {
    // equality masks per word (15 ops each)
    unsigned e0[8], e1[8];
    {
      unsigned n0 = ~p0l, n1 = ~p1l, n2 = ~p2l;
      unsigned a00 = n1 & n0, a01 = n1 & p0l, a10 = p1l & n0, a11 = p1l & p0l;
      e0[0] = n2 & a00; e0[1] = n2 & a01; e0[2] = n2 & a10; e0[3] = n2 & a11;
      e0[4] = p2l & a00; e0[5] = p2l & a01; e0[6] = p2l & a10; e0[7] = p2l & a11;
    }
    {
      unsigned n0 = ~p0h, n1 = ~p1h, n2 = ~p2h;
      unsigned a00 = n1 & n0, a01 = n1 & p0h, a10 = p1h & n0, a11 = p1h & p0h;
      e1[0] = n2 & a00; e1[1] = n2 & a01; e1[2] = n2 & a10; e1[3] = n2 & a11;
      e1[4] = p2h & a00; e1[5] = p2h & a01; e1[6] = p2h & a10; e1[7] = p2h & a11;
    }

    // vertical 2-bit 3-count per bin per word; rows +-1 via DPP wave shifts
    unsigned VL0[8], VH0[8], VL1[8], VH1[8];
#pragma unroll
    for (int b = 0; b < 8; ++b) {
      unsigned eu = dppUp(e0[b]), ed = dppDn(e0[b]);
      if (topE) eu = pTop ? e0[b] : eu;
      if (botE) ed = pBot ? e0[b] : ed;
      unsigned t = eu ^ e0[b];
      VL0[b] = t ^ ed; VH0[b] = bfi(t, ed, e0[b]);   // majority(eu,e,ed)
      eu = dppUp(e1[b]); ed = dppDn(e1[b]);
      if (topE) eu = pTop ? e1[b] : eu;
      if (botE) ed = pBot ? e1[b] : ed;
      t = eu ^ e1[b];
      VL1[b] = t ^ ed; VH1[b] = bfi(t, ed, e1[b]);
    }

    // horizontal u64 funnel + 2b+2b+2b->4b adder + running strict-> argmax
    unsigned b0l, b1l, b2l, b3l, j0l, j1l, j2l;
    unsigned b0h, b1h, b2h, b3h, j0h, j1h, j2h;
#pragma unroll
    for (int b = 0; b < 8; ++b) {
      unsigned AL0 = VL0[b] << 1,              AL1 = alignb(VL1[b], VL0[b], 31);
      unsigned AH0 = VH0[b] << 1,              AH1 = alignb(VH1[b], VH0[b], 31);
      unsigned CL0 = alignb(VL1[b], VL0[b], 1), CL1 = VL1[b] >> 1;
      unsigned CH0 = alignb(VH1[b], VH0[b], 1), CH1 = VH1[b] >> 1;
      if (lxE) { AL0 = bfi(0x100u, VL0[b], AL0); AH0 = bfi(0x100u, VH0[b], AH0); }
      if (rxE) { CL1 = bfi(0x00800000u, VL1[b], CL1); CH1 = bfi(0x00800000u, VH1[b], CH1); }

      // word0 adder: (A + V) + C -> t0..t3
      unsigned s0 = AL0 ^ VL0[b], cc = AL0 & VL0[b];
      unsigned u  = AH0 ^ VH0[b];
      unsigned s1 = u ^ cc, s2 = bfi(u, cc, VH0[b]);
      unsigned t0 = s0 ^ CL0, k0 = s0 & CL0, vv = s1 ^ CH0;
      unsigned t1 = vv ^ k0;
      unsigned k1 = bfi(vv, k0, CH0);
      unsigned t2 = s2 ^ k1, t3 = s2 & k1;
      // word1 adder -> q0..q3
      s0 = AL1 ^ VL1[b]; cc = AL1 & VL1[b];
      u  = AH1 ^ VH1[b];
      s1 = u ^ cc; s2 = bfi(u, cc, VH1[b]);
      unsigned q0 = s0 ^ CL1; k0 = s0 & CL1; vv = s1 ^ CH1;
      unsigned q1 = vv ^ k0;
      k1 = bfi(vv, k0, CH1);
      unsigned q2 = s2 ^ k1, q3 = s2 & k1;

      if (b == 0) {
        b0l = t0; b1l = t1; b2l = t2; b3l = t3; j0l = j1l = j2l = 0;
        b0h = q0; b1h = q1; b2h = q2; b3h = q3; j0h = j1h = j2h = 0;
      } else {
        unsigned d, g;
        d = t0 ^ b0l; g = d & t0;
        d = t1 ^ b1l; g = bfi(d, d & t1, g);
        d = t2 ^ b2l; g = bfi(d, d & t2, g);
        d = t3 ^ b3l; g = bfi(d, d & t3, g);
        b0l = bfi(g, t0, b0l); b1l = bfi(g, t1, b1l);
        b2l = bfi(g, t2, b2l); b3l = bfi(g, t3, b3l);
        j0l = (b & 1) ? (j0l | g) : bfi(g, 0u, j0l);
        j1l = (b & 2) ? (j1l | g) : bfi(g, 0u, j1l);
        j2l = (b & 4) ? (j2l | g) : bfi(g, 0u, j2l);
        d = q0 ^ b0h; g = d & q0;
        d = q1 ^ b1h; g = bfi(d, d & q1, g);
        d = q2 ^ b2h; g = bfi(d, d & q2, g);
        d = q3 ^ b3h; g = bfi(d, d & q3, g);
        b0h = bfi(g, q0, b0h); b1h = bfi(g, q1, b1h);
        b2h = bfi(g, q2, b2h); b3h = bfi(g, q3, b3h);
        j0h = (b & 1) ? (j0h | g) : bfi(g, 0u, j0h);
        j1h = (b & 2) ? (j1h | g) : bfi(g, 0u, j1h);
        j2h = (b & 4) ? (j2h | g) : bfi(g, 0u, j2h);
      }
    }
    p0l = j0l; p1l = j1l; p2l = j2l;
    p0h = j0h; p1h = j1h; p2h = j2h;
  }

  // ---- store: lanes 8..55 = output rows; word0 bits 8..31 -> gx bx*48+0..23,
  // word1 bits 0..23 -> gx bx*48+24..47.
  if (lane >= 8 && lane < 56) {
    float* orow = out + (size_t)bz * IMG * IMG + (size_t)gyu * IMG + bx * 48;
#pragma unroll
    for (int g = 0; g < 6; ++g) {
      const int j = 8 + 4 * g;
      float4 f;
      f.x = (float)(((p0l >> (j + 0)) & 1u) | (((p1l >> (j + 0)) & 1u) << 1) | (((p2l >> (j + 0)) & 1u) << 2));
      f.y = (float)(((p0l >> (j + 1)) & 1u) | (((p1l >> (j + 1)) & 1u) << 1) | (((p2l >> (j + 1)) & 1u) << 2));
      f.z = (float)(((p0l >> (j + 2)) & 1u) | (((p1l >> (j + 2)) & 1u) << 1) | (((p2l >> (j + 2)) & 1u) << 2));
      f.w = (float)(((p0l >> (j + 3)) & 1u) | (((p1l >> (j + 3)) & 1u) << 1) | (((p2l >> (j + 3)) & 1u) << 2));
      *reinterpret_cast<float4*>(orow + 4 * g) = f;
    }
#pragma unroll
    for (int g = 0; g < 6; ++g) {
      const int j = 4 * g;
      float4 f;
      f.x = (float)(((p0h >> (j + 0)) & 1u) | (((p1h >> (j + 0)) & 1u) << 1) | (((p2h >> (j + 0)) & 1u) << 2));
      f.y = (float)(((p0h >> (j + 1)) & 1u) | (((p1h >> (j + 1)) & 1u) << 1) | (((p2h >> (j + 1)) & 1u) << 2));
      f.z = (float)(((p0h >> (j + 2)) & 1u) | (((p1h >> (j + 2)) & 1u) << 1) | (((p2h >> (j + 2)) & 1u) << 2));
      f.w = (float)(((p0h >> (j + 3)) & 1u) | (((p1h >> (j + 3)) & 1u) << 1) | (((p2h >> (j + 3)) & 1u) << 2));
      *reinterpret_cast<float4*>(orow + 24 + 4 * g) = f;
    }
  }
}

extern "C" void kernel_launch(void* const* d_in, const int* in_sizes, int n_in,
                              void* d_out, int out_size, void* d_ws, size_t ws_size,
                              hipStream_t stream) {
  const float* clusters = (const float*)d_in[0];
  (void)in_sizes; (void)n_in; (void)out_size; (void)d_ws; (void)ws_size;

  // 4 independent wave-tiles per 256-thread block; grid.x*4 = 16 x-tiles.
  dim3 grid(4, NBY, 8);
  fused_dpp<<<grid, 256, 0, stream>>>(clusters, (float*)d_out);
}

// Round 11
// 36.649 us; speedup vs baseline: 1.4113x; 1.0993x over previous
//
#include <hip/hip_runtime.h>

// 3x3 majority, replicate pad, 8 bins, ties -> smallest, 8 fused iterations.
// Bit-sliced planes (3 bits/label). Lane = one FULL tile row of 64 px as a
// u64 (two u32 words). Wave = 64x64 input tile -> 48x48 output (halo 8).
// Vertical: DPP wave_shr1/wave_shl1 (VALU-pipe, no DS, no barriers).
// Horizontal: in-lane u64 funnel shifts. Argmax: bitwise tournament
// (depth 3, strict >, scan order => first max = smallest label).
// R11 changes vs R10: __launch_bounds__(256,2) to raise the VGPR budget
// (R10 compiled to 44 VGPR => serialized dep chains, VALUBusy 58% at the
// 2-waves/SIMD grid ceiling), and tournament argmax instead of the linear
// scan for shorter critical path / more ILP.

static constexpr int IMG = 768;
static constexpr int NBX = 16;   // 768/48 x-tiles
static constexpr int NBY = 16;   // 768/48 y-tiles

__device__ __forceinline__ unsigned bfi(unsigned m, unsigned a, unsigned b) {
  return (a & m) | (b & ~m);     // v_bfi_b32
}
__device__ __forceinline__ unsigned dppUp(unsigned x) {   // lane i <- lane i-1
  return (unsigned)__builtin_amdgcn_update_dpp((int)x, (int)x, 0x138, 0xF, 0xF, false);
}
__device__ __forceinline__ unsigned dppDn(unsigned x) {   // lane i <- lane i+1
  return (unsigned)__builtin_amdgcn_update_dpp((int)x, (int)x, 0x130, 0xF, 0xF, false);
}
__device__ __forceinline__ unsigned alignb(unsigned hi, unsigned lo, int s) {
  return __builtin_amdgcn_alignbit(hi, lo, s);   // ((hi:lo) >> s) low 32
}

struct C4 { unsigned b0, b1, b2, b3; };

__device__ __forceinline__ unsigned gt4(const C4& x, const C4& y) {  // x > y
  unsigned d = x.b0 ^ y.b0;
  unsigned g = d & x.b0;
  d = x.b1 ^ y.b1; g = bfi(d, d & x.b1, g);
  d = x.b2 ^ y.b2; g = bfi(d, d & x.b2, g);
  d = x.b3 ^ y.b3; g = bfi(d, d & x.b3, g);
  return g;
}
__device__ __forceinline__ C4 sel4(unsigned G, const C4& x, const C4& y) {
  C4 r; r.b0 = bfi(G, x.b0, y.b0); r.b1 = bfi(G, x.b1, y.b1);
  r.b2 = bfi(G, x.b2, y.b2); r.b3 = bfi(G, x.b3, y.b3); return r;
}
__device__ __forceinline__ void tourn8(const C4 c[8],
                                       unsigned& o0, unsigned& o1, unsigned& o2) {
  unsigned g01 = gt4(c[1], c[0]); C4 w01 = sel4(g01, c[1], c[0]);
  unsigned g23 = gt4(c[3], c[2]); C4 w23 = sel4(g23, c[3], c[2]);
  unsigned gA  = gt4(w23, w01);   C4 wA  = sel4(gA, w23, w01);
  unsigned iA0 = bfi(gA, g23, g01), iA1 = gA;
  unsigned g45 = gt4(c[5], c[4]); C4 w45 = sel4(g45, c[5], c[4]);
  unsigned g67 = gt4(c[7], c[6]); C4 w67 = sel4(g67, c[7], c[6]);
  unsigned gB  = gt4(w67, w45);   C4 wB  = sel4(gB, w67, w45);
  unsigned iB0 = bfi(gB, g67, g45), iB1 = gB;
  unsigned gR  = gt4(wB, wA);
  o0 = bfi(gR, iB0, iA0); o1 = bfi(gR, iB1, iA1); o2 = gR;
}

__global__ __launch_bounds__(256, 2) void fused_dpp(
    const float* __restrict__ in, float* __restrict__ out) {
  const int wv = threadIdx.x >> 6;
  const int lane = threadIdx.x & 63;
  const int bx = blockIdx.x * 4 + wv;          // 0..15
  const int by = blockIdx.y, bz = blockIdx.z;

  const float* img = in + (size_t)bz * IMG * IMG;
  const int gyu = by * 48 - 8 + lane;          // unclamped global row

  // ---- stage: one clamped 64-px row -> 6 plane words
  unsigned p0l = 0, p1l = 0, p2l = 0, p0h = 0, p1h = 0, p2h = 0;
  {
    int gy = gyu < 0 ? 0 : (gyu > IMG - 1 ? IMG - 1 : gyu);
    const float* rp = img + (size_t)gy * IMG;
    const int gx0 = bx * 48 - 8;
    if (gx0 >= 0 && gx0 + 64 <= IMG) {
#pragma unroll
      for (int g = 0; g < 8; ++g) {
        float4 f = *reinterpret_cast<const float4*>(rp + gx0 + 4 * g);
        unsigned u0 = (unsigned)(int)f.x, u1 = (unsigned)(int)f.y;
        unsigned u2 = (unsigned)(int)f.z, u3 = (unsigned)(int)f.w;
        p0l |= ((u0 & 1u) | ((u1 & 1u) << 1) | ((u2 & 1u) << 2) | ((u3 & 1u) << 3)) << (4 * g);
        p1l |= (((u0 >> 1) & 1u) | (((u1 >> 1) & 1u) << 1) | (((u2 >> 1) & 1u) << 2) | (((u3 >> 1) & 1u) << 3)) << (4 * g);
        p2l |= (((u0 >> 2) & 1u) | (((u1 >> 2) & 1u) << 1) | (((u2 >> 2) & 1u) << 2) | (((u3 >> 2) & 1u) << 3)) << (4 * g);
      }
#pragma unroll
      for (int g = 0; g < 8; ++g) {
        float4 f = *reinterpret_cast<const float4*>(rp + gx0 + 32 + 4 * g);
        unsigned u0 = (unsigned)(int)f.x, u1 = (unsigned)(int)f.y;
        unsigned u2 = (unsigned)(int)f.z, u3 = (unsigned)(int)f.w;
        p0h |= ((u0 & 1u) | ((u1 & 1u) << 1) | ((u2 & 1u) << 2) | ((u3 & 1u) << 3)) << (4 * g);
        p1h |= (((u0 >> 1) & 1u) | (((u1 >> 1) & 1u) << 1) | (((u2 >> 1) & 1u) << 2) | (((u3 >> 1) & 1u) << 3)) << (4 * g);
        p2h |= (((u0 >> 2) & 1u) | (((u1 >> 2) & 1u) << 1) | (((u2 >> 2) & 1u) << 2) | (((u3 >> 2) & 1u) << 3)) << (4 * g);
      }
    } else {
#pragma unroll
      for (int j = 0; j < 32; ++j) {
        int gx = gx0 + j; gx = gx < 0 ? 0 : (gx > IMG - 1 ? IMG - 1 : gx);
        unsigned u = (unsigned)(int)rp[gx];
        p0l |= (u & 1u) << j; p1l |= ((u >> 1) & 1u) << j; p2l |= ((u >> 2) & 1u) << j;
        gx = gx0 + 32 + j; gx = gx < 0 ? 0 : (gx > IMG - 1 ? IMG - 1 : gx);
        u = (unsigned)(int)rp[gx];
        p0h |= (u & 1u) << j; p1h |= ((u >> 1) & 1u) << j; p2h |= ((u >> 2) & 1u) << j;
      }
    }
  }

  const bool topE = (by == 0), botE = (by == NBY - 1);
  const bool lxE = (bx == 0), rxE = (bx == NBX - 1);
  const bool pTop = (lane == 8);    // image row 0 (gyu==0) when by==0
  const bool pBot = (lane == 55);   // image row 767 when by==15

#pragma unroll 1
  for (int it = 0; it < 8; ++it) {
    // equality masks per word (15 ops each)
    unsigned e0[8], e1[8];
    {
      unsigned n0 = ~p0l, n1 = ~p1l, n2 = ~p2l;
      unsigned a00 = n1 & n0, a01 = n1 & p0l, a10 = p1l & n0, a11 = p1l & p0l;
      e0[0] = n2 & a00; e0[1] = n2 & a01; e0[2] = n2 & a10; e0[3] = n2 & a11;
      e0[4] = p2l & a00; e0[5] = p2l & a01; e0[6] = p2l & a10; e0[7] = p2l & a11;
    }
    {
      unsigned n0 = ~p0h, n1 = ~p1h, n2 = ~p2h;
      unsigned a00 = n1 & n0, a01 = n1 & p0h, a10 = p1h & n0, a11 = p1h & p0h;
      e1[0] = n2 & a00; e1[1] = n2 & a01; e1[2] = n2 & a10; e1[3] = n2 & a11;
      e1[4] = p2h & a00; e1[5] = p2h & a01; e1[6] = p2h & a10; e1[7] = p2h & a11;
    }

    // vertical 2-bit 3-count per bin per word; rows +-1 via DPP wave shifts
    unsigned VL0[8], VH0[8], VL1[8], VH1[8];
#pragma unroll
    for (int b = 0; b < 8; ++b) {
      unsigned eu = dppUp(e0[b]), ed = dppDn(e0[b]);
      if (topE) eu = pTop ? e0[b] : eu;
      if (botE) ed = pBot ? e0[b] : ed;
      unsigned t = eu ^ e0[b];
      VL0[b] = t ^ ed; VH0[b] = bfi(t, ed, e0[b]);   // majority(eu,e,ed)
      eu = dppUp(e1[b]); ed = dppDn(e1[b]);
      if (topE) eu = pTop ? e1[b] : eu;
      if (botE) ed = pBot ? e1[b] : ed;
      t = eu ^ e1[b];
      VL1[b] = t ^ ed; VH1[b] = bfi(t, ed, e1[b]);
    }

    // horizontal u64 funnel + 2b+2b+2b->4b adder -> per-bin 4-bit counts
    C4 c0[8], c1[8];
#pragma unroll
    for (int b = 0; b < 8; ++b) {
      unsigned AL0 = VL0[b] << 1,               AL1 = alignb(VL1[b], VL0[b], 31);
      unsigned AH0 = VH0[b] << 1,               AH1 = alignb(VH1[b], VH0[b], 31);
      unsigned CL0 = alignb(VL1[b], VL0[b], 1), CL1 = VL1[b] >> 1;
      unsigned CH0 = alignb(VH1[b], VH0[b], 1), CH1 = VH1[b] >> 1;
      if (lxE) { AL0 = bfi(0x100u, VL0[b], AL0); AH0 = bfi(0x100u, VH0[b], AH0); }
      if (rxE) { CL1 = bfi(0x00800000u, VL1[b], CL1); CH1 = bfi(0x00800000u, VH1[b], CH1); }

      // word0 adder: (A + V) + C -> c0[b]
      unsigned s0 = AL0 ^ VL0[b], cc = AL0 & VL0[b];
      unsigned u  = AH0 ^ VH0[b];
      unsigned s1 = u ^ cc, s2 = bfi(u, cc, VH0[b]);
      unsigned t0 = s0 ^ CL0, k0 = s0 & CL0, vv = s1 ^ CH0;
      c0[b].b0 = t0; c0[b].b1 = vv ^ k0;
      unsigned k1 = bfi(vv, k0, CH0);
      c0[b].b2 = s2 ^ k1; c0[b].b3 = s2 & k1;
      // word1 adder -> c1[b]
      s0 = AL1 ^ VL1[b]; cc = AL1 & VL1[b];
      u  = AH1 ^ VH1[b];
      s1 = u ^ cc; s2 = bfi(u, cc, VH1[b]);
      unsigned q0 = s0 ^ CL1; k0 = s0 & CL1; vv = s1 ^ CH1;
      c1[b].b0 = q0; c1[b].b1 = vv ^ k0;
      k1 = bfi(vv, k0, CH1);
      c1[b].b2 = s2 ^ k1; c1[b].b3 = s2 & k1;
    }

    // tournament argmax per word (depth 3; first max = smallest label)
    tourn8(c0, p0l, p1l, p2l);
    tourn8(c1, p0h, p1h, p2h);
  }

  // ---- store: lanes 8..55 = output rows; word0 bits 8..31 -> gx bx*48+0..23,
  // word1 bits 0..23 -> gx bx*48+24..47.
  if (lane >= 8 && lane < 56) {
    float* orow = out + (size_t)bz * IMG * IMG + (size_t)gyu * IMG + bx * 48;
#pragma unroll
    for (int g = 0; g < 6; ++g) {
      const int j = 8 + 4 * g;
      float4 f;
      f.x = (float)(((p0l >> (j + 0)) & 1u) | (((p1l >> (j + 0)) & 1u) << 1) | (((p2l >> (j + 0)) & 1u) << 2));
      f.y = (float)(((p0l >> (j + 1)) & 1u) | (((p1l >> (j + 1)) & 1u) << 1) | (((p2l >> (j + 1)) & 1u) << 2));
      f.z = (float)(((p0l >> (j + 2)) & 1u) | (((p1l >> (j + 2)) & 1u) << 1) | (((p2l >> (j + 2)) & 1u) << 2));
      f.w = (float)(((p0l >> (j + 3)) & 1u) | (((p1l >> (j + 3)) & 1u) << 1) | (((p2l >> (j + 3)) & 1u) << 2));
      *reinterpret_cast<float4*>(orow + 4 * g) = f;
    }
#pragma unroll
    for (int g = 0; g < 6; ++g) {
      const int j = 4 * g;
      float4 f;
      f.x = (float)(((p0h >> (j + 0)) & 1u) | (((p1h >> (j + 0)) & 1u) << 1) | (((p2h >> (j + 0)) & 1u) << 2));
      f.y = (float)(((p0h >> (j + 1)) & 1u) | (((p1h >> (j + 1)) & 1u) << 1) | (((p2h >> (j + 1)) & 1u) << 2));
      f.z = (float)(((p0h >> (j + 2)) & 1u) | (((p1h >> (j + 2)) & 1u) << 1) | (((p2h >> (j + 2)) & 1u) << 2));
      f.w = (float)(((p0h >> (j + 3)) & 1u) | (((p1h >> (j + 3)) & 1u) << 1) | (((p2h >> (j + 3)) & 1u) << 2));
      *reinterpret_cast<float4*>(orow + 24 + 4 * g) = f;
    }
  }
}

extern "C" void kernel_launch(void* const* d_in, const int* in_sizes, int n_in,
                              void* d_out, int out_size, void* d_ws, size_t ws_size,
                              hipStream_t stream) {
  const float* clusters = (const float*)d_in[0];
  (void)in_sizes; (void)n_in; (void)out_size; (void)d_ws; (void)ws_size;

  // 4 independent wave-tiles per 256-thread block; grid.x*4 = 16 x-tiles.
  dim3 grid(4, NBY, 8);
  fused_dpp<<<grid, 256, 0, stream>>>(clusters, (float*)d_out);
}